// Round 2
// baseline (511.773 us; speedup 1.0000x reference)
//
#include <hip/hip_runtime.h>
#include <cstdint>
#include <cmath>

// GPT-2 block: B=8, S=1024, D=1024, H=16, Hd=64.
// LN1 -> qkv GEMM -> MFMA flash attention -> proj GEMM(+res) -> LN2
//     -> fc GEMM(+fast GELU) -> proj2 GEMM(+res) -> out (fp32)
// GEMM v2: bf16 MFMA 16x16x32, BM=256, BK=64, 8 waves, m201-faithful phases:
//   BOTH A and B staged via global_load_lds (NO global->VGPR loads in the
//   main loop => zero compiler-inserted vmcnt; the only vmcnt waits are the
//   hand-counted ones). One s_waitcnt vmcnt(L) per K-tile (full-tile latency
//   cover), double-buffered LDS for A and B, per-phase {ds_read; barrier;
//   setprio MFMA; barrier}.
//   A: XOR-chunk swizzle via pre-swizzled global source (0 conflicts).
//   B: pre-packed fragment-major => LDS image is a linear copy; frag reads
//      are stride-1 ds_read_b128 (conflict-free).

#define Bb 8
#define Ss 1024
#define Dd 1024
#define Hh 16
#define HD 64
#define MTOK 8192  // B*S

typedef __attribute__((ext_vector_type(4))) float  floatx4;
typedef __attribute__((ext_vector_type(8))) short  short8;
typedef __attribute__((ext_vector_type(4))) short  short4v;

__device__ __forceinline__ float bf2f(unsigned short u) {
    return __uint_as_float(((unsigned int)u) << 16);
}
__device__ __forceinline__ unsigned short f2bf(float f) {
    unsigned int u = __float_as_uint(f);
    u += 0x7FFFu + ((u >> 16) & 1u);   // RNE
    return (unsigned short)(u >> 16);
}

__device__ __forceinline__ void gl2lds16(const void* g, void* l) {
    __builtin_amdgcn_global_load_lds(
        (__attribute__((address_space(1))) void*)(g),
        (__attribute__((address_space(3))) void*)(l),
        16, 0, 0);
}

template <int N> __device__ __forceinline__ void wait_vmcnt() {
    if constexpr (N == 6)       asm volatile("s_waitcnt vmcnt(6)"  ::: "memory");
    else if constexpr (N == 8)  asm volatile("s_waitcnt vmcnt(8)"  ::: "memory");
    else if constexpr (N == 12) asm volatile("s_waitcnt vmcnt(12)" ::: "memory");
    else                        asm volatile("s_waitcnt vmcnt(0)"  ::: "memory");
}

// ---------------- weight pack: fp32 [K][N] -> bf16 fragment-major ----------
// P[((nt*KC + kc)*64 + lane)*8 + j] = bf16(W[(kc*32 + (lane>>4)*8 + j)*N + nt*16 + (lane&15)])
__global__ __launch_bounds__(256) void pack_w(
    const float* __restrict__ W, unsigned short* __restrict__ P, int K, int N)
{
    const int KC = K >> 5;
    int tile = blockIdx.x * 4 + (threadIdx.x >> 6);
    int lane = threadIdx.x & 63;
    int nt = tile / KC, kc = tile - nt * KC;
    int l16 = lane & 15, quad = lane >> 4;
    const float* src = W + (size_t)(kc * 32 + quad * 8) * N + nt * 16 + l16;
    short8 o;
#pragma unroll
    for (int j = 0; j < 8; ++j) o[j] = (short)f2bf(src[(size_t)j * N]);
    *(short8*)(P + ((size_t)(nt * KC + kc) * 64 + lane) * 8) = o;
}

// ---------------- layernorm fp32 -> bf16 ----------------
__global__ __launch_bounds__(256) void layernorm_bf16(
    const float* __restrict__ X, const float* __restrict__ g,
    const float* __restrict__ b, unsigned short* __restrict__ Y)
{
    int row = blockIdx.x, t = threadIdx.x;
    const float4* xr = (const float4*)(X + (size_t)row * Dd);
    float4 v = xr[t];
    float s  = v.x + v.y + v.z + v.w;
    float s2 = v.x * v.x + v.y * v.y + v.z * v.z + v.w * v.w;
#pragma unroll
    for (int off = 32; off >= 1; off >>= 1) {
        s  += __shfl_down(s, off, 64);
        s2 += __shfl_down(s2, off, 64);
    }
    __shared__ float red[8];
    int wave = t >> 6, lane = t & 63;
    if (lane == 0) { red[wave] = s; red[4 + wave] = s2; }
    __syncthreads();
    float ts  = red[0] + red[1] + red[2] + red[3];
    float ts2 = red[4] + red[5] + red[6] + red[7];
    float mu  = ts * (1.0f / Dd);
    float var = ts2 * (1.0f / Dd) - mu * mu;
    float rstd = rsqrtf(var + 1e-5f);
    float4 gv = ((const float4*)g)[t];
    float4 bv = ((const float4*)b)[t];
    ushort4 o;
    o.x = f2bf((v.x - mu) * rstd * gv.x + bv.x);
    o.y = f2bf((v.y - mu) * rstd * gv.y + bv.y);
    o.z = f2bf((v.z - mu) * rstd * gv.z + bv.z);
    o.w = f2bf((v.w - mu) * rstd * gv.w + bv.w);
    ((ushort4*)(Y + (size_t)row * Dd))[t] = o;
}

// ---------------- GEMM v2: C = A[M,K] * W + bias --------------------------
// MODE 0: out bf16 = A@W + bias
// MODE 1: out fp32 = A@W + bias + res
// MODE 2: out bf16 = gelu_new(A@W + bias)
// WM: waves along M (2 or 4). WN = 8/WM. NI = 4 B-frags per wave.
//   WM=2: BN=256, MI=8, 4 phases/K-tile, LDS 128 KB.
//   WM=4: BN=128, MI=4, 2 phases/K-tile, LDS 96 KB.

#define V2STAGE(TT) do {                                                      \
    const int ab_ = ((TT) & 1) * 16384;                                       \
    _Pragma("unroll")                                                         \
    for (int r_ = 0; r_ < 4; ++r_)                                            \
        gl2lds16(sAp[r_] + (size_t)(TT) * 64,                                 \
                 As + ab_ + (tid + r_ * 512) * 8);                            \
    const int bb_ = ((TT) & 1) * (BN * 64);                                   \
    _Pragma("unroll")                                                         \
    for (int r_ = 0; r_ < LB; ++r_)                                           \
        gl2lds16(sBp[r_] + (size_t)(TT) * 1024,                               \
                 Bs + bb_ + (wave * LB + r_) * 512 + lane * 8);               \
} while (0)

template <int MODE, int WM>
__global__ __launch_bounds__(512, 2) void gemm_v2(
    const unsigned short* __restrict__ A,   // [M][K] bf16 row-major
    const unsigned short* __restrict__ BP,  // packed weight frags
    const float* __restrict__ bias,
    const float* __restrict__ res,
    void* __restrict__ out,
    int M, int N, int K)
{
    constexpr int WN  = 8 / WM;
    constexpr int NI  = 4;
    constexpr int BN  = WN * NI * 16;           // 256 (WM=2) or 128 (WM=4)
    constexpr int MI  = 16 / WM;                // 8 or 4 A-frags per wave
    constexpr int NPH = (MI * NI * 2) / 16;     // 4 or 2 phases per K-tile
    constexpr int LB  = (BN * 64 * 2) / (512 * 16);  // B loads/thread: 4 or 2
    constexpr int L   = 4 + LB;                 // loads/thread/K-tile: 8 or 6

    __shared__ short As[2 * 256 * 64];          // 64 KB double-buffered A
    __shared__ short Bs[2 * BN * 64];           // 64/32 KB double-buffered B

    const int tid  = threadIdx.x;
    const int wave = tid >> 6, lane = tid & 63;
    const int quad = lane >> 4, l16 = lane & 15;
    const int wrow = wave / WN, wcol = wave % WN;
    const int swA = l16 & 7;
    const size_t rowA0 = (size_t)blockIdx.x * 256;
    const int KC = K >> 5;   // 32-row k-chunks
    const int NT = K >> 6;   // 64-deep K tiles

    // A staging sources (4 x 16B/thread/tile), XOR chunk swizzle on the
    // global side so the linear gl2lds write produces the swizzled layout.
    const unsigned short* sAp[4];
#pragma unroll
    for (int r = 0; r < 4; ++r) {
        int idx = tid + r * 512;
        int sr  = idx >> 3;
        int sc  = ((idx & 7) ^ (sr & 7)) * 8;
        sAp[r] = A + (rowA0 + sr) * K + sc;
    }
    // B staging sources: chunk c = wave*LB + r <-> (nt_local = c>>1, ks = c&1)
    const unsigned short* sBp[LB];
#pragma unroll
    for (int r = 0; r < LB; ++r) {
        int c = wave * LB + r;
        sBp[r] = BP + ((size_t)(blockIdx.y * (BN / 16) + (c >> 1)) * KC + (c & 1)) * 512
                    + lane * 8;
    }

    // fragment read bases
    const int aB = (wrow * (MI * 16) + l16) * 64;
    const int bB = wcol * NI * 1024 + lane * 8;

    floatx4 acc[MI][NI] = {};

    V2STAGE(0);

    for (int t = 0; t < NT; ++t) {
        const int tn = (t + 1 < NT) ? t + 1 : t;  // tail: re-stage same tile
        V2STAGE(tn);                              // (uniform vmcnt counts)
        wait_vmcnt<L>();                          // tile t done; t+1 in flight
        __builtin_amdgcn_s_barrier();
        const int abuf = (t & 1) * 16384;
        const int bbuf = (t & 1) * (BN * 64);
        short8 bfr[NI];
#pragma unroll
        for (int ph = 0; ph < NPH; ++ph) {
            const int ks = (NPH == 4) ? (ph >> 1) : ph;
            const int mh = (NPH == 4) ? (ph & 1) : 0;
            const int coff = ((ks * 4 + quad) ^ swA) * 8;
            short8 af[4];
#pragma unroll
            for (int i = 0; i < 4; ++i)
                af[i] = *(const short8*)(As + abuf + aB + mh * 4096
                                         + i * 1024 + coff);
            if (mh == 0) {
#pragma unroll
                for (int n = 0; n < NI; ++n)
                    bfr[n] = *(const short8*)(Bs + bbuf + bB + (n * 2 + ks) * 512);
            }
            __builtin_amdgcn_s_barrier();
            __builtin_amdgcn_s_setprio(1);
#pragma unroll
            for (int i = 0; i < 4; ++i)
#pragma unroll
                for (int n = 0; n < NI; ++n)
                    acc[mh * 4 + i][n] = __builtin_amdgcn_mfma_f32_16x16x32_bf16(
                        af[i], bfr[n], acc[mh * 4 + i][n], 0, 0, 0);
            __builtin_amdgcn_s_setprio(0);
            __builtin_amdgcn_s_barrier();
        }
    }

    // epilogue
    const size_t colB = (size_t)blockIdx.y * BN + wcol * (NI * 16);
#pragma unroll
    for (int mi = 0; mi < MI; ++mi) {
#pragma unroll
        for (int ni = 0; ni < NI; ++ni) {
            size_t row = rowA0 + wrow * (MI * 16) + mi * 16 + quad * 4;
            size_t col = colB + ni * 16 + l16;
            float bc = bias[col];
#pragma unroll
            for (int r = 0; r < 4; ++r) {
                float v = acc[mi][ni][r] + bc;
                if (MODE == 0) {
                    ((unsigned short*)out)[(row + r) * N + col] = f2bf(v);
                } else if (MODE == 1) {
                    ((float*)out)[(row + r) * N + col] = v + res[(row + r) * N + col];
                } else {
                    float u = 0.7978845608028654f * (v + 0.044715f * v * v * v);
                    float e = __builtin_amdgcn_exp2f(-2.8853900817779268f * u);
                    float gl = v * __builtin_amdgcn_rcpf(1.0f + e);
                    ((unsigned short*)out)[(row + r) * N + col] = f2bf(gl);
                }
            }
        }
    }
}

// ---------------- MFMA flash attention (causal) ----------------
__global__ __launch_bounds__(256, 2) void attn_mfma(
    const unsigned short* __restrict__ qkv,  // [B*S][3072] bf16 q|k|v
    unsigned short* __restrict__ ctx)        // [B*S][1024] bf16
{
    __shared__ unsigned short Ks[64 * 72];
    __shared__ unsigned short VT[64 * 72];
    __shared__ unsigned short PT[128 * 72];

    const int tid  = threadIdx.x;
    const int wave = tid >> 6, lane = tid & 63;
    const int quad = lane >> 4, l16 = lane & 15;
    const int blk = blockIdx.x;
    const int c4 = blk & 3, h = (blk >> 2) & 15, b = blk >> 6;
    const size_t tokbase = (size_t)b * Ss;

    const int skey = tid & 63;
    const int sseg = tid >> 6;

    for (int ci = 0; ci < 2; ++ci) {
        const int chunk = ci ? (7 - c4) : c4;
        const int q0 = chunk * 128;

        short8 qf[2][2];
#pragma unroll
        for (int nb = 0; nb < 2; ++nb)
#pragma unroll
            for (int ks = 0; ks < 2; ++ks) {
                const short8* qp = (const short8*)(qkv
                    + (tokbase + q0 + wave * 32 + nb * 16 + l16) * 3072
                    + h * HD + ks * 32 + quad * 8);
                short8 v = *qp, o;
#pragma unroll
                for (int j = 0; j < 8; ++j)
                    o[j] = (short)f2bf(bf2f((unsigned short)v[j]) * 0.18033688011112042f);
                qf[nb][ks] = o;
            }

        floatx4 Oacc[4][2] = {};
        float mrow[2] = {-3.0e38f, -3.0e38f};
        float lrow[2] = {0.f, 0.f};

        const int nkt = 2 * (chunk + 1);
        for (int kt = 0; kt < nkt; ++kt) {
            __syncthreads();
            {
                const short8* kp = (const short8*)(qkv
                    + (tokbase + kt * 64 + skey) * 3072 + Dd + h * HD + sseg * 16);
                short8 k0 = kp[0], k1 = kp[1];
                *(short8*)(Ks + skey * 72 + sseg * 16)     = k0;
                *(short8*)(Ks + skey * 72 + sseg * 16 + 8) = k1;
                const short8* vp = (const short8*)(qkv
                    + (tokbase + kt * 64 + skey) * 3072 + 2 * Dd + h * HD + sseg * 16);
                short8 v0 = vp[0], v1 = vp[1];
#pragma unroll
                for (int j = 0; j < 8; ++j) {
                    VT[(sseg * 16 + j) * 72 + skey]     = (unsigned short)v0[j];
                    VT[(sseg * 16 + 8 + j) * 72 + skey] = (unsigned short)v1[j];
                }
            }
            __syncthreads();

            floatx4 sacc[4][2] = {};
#pragma unroll
            for (int ks = 0; ks < 2; ++ks) {
                short8 af[4];
#pragma unroll
                for (int mi = 0; mi < 4; ++mi)
                    af[mi] = *(const short8*)(Ks + (mi * 16 + l16) * 72 + ks * 32 + quad * 8);
#pragma unroll
                for (int mi = 0; mi < 4; ++mi)
#pragma unroll
                    for (int nb = 0; nb < 2; ++nb)
                        sacc[mi][nb] = __builtin_amdgcn_mfma_f32_16x16x32_bf16(
                            af[mi], qf[nb][ks], sacc[mi][nb], 0, 0, 0);
            }

            if (kt >= 2 * chunk) {
                const int dk = (kt - 2 * chunk) * 64;
#pragma unroll
                for (int nb = 0; nb < 2; ++nb) {
                    int qrow = wave * 32 + nb * 16 + l16;
#pragma unroll
                    for (int mi = 0; mi < 4; ++mi)
#pragma unroll
                        for (int r = 0; r < 4; ++r)
                            if (dk + mi * 16 + quad * 4 + r > qrow)
                                sacc[mi][nb][r] = -3.0e38f;
                }
            }

#pragma unroll
            for (int nb = 0; nb < 2; ++nb) {
                float mx = sacc[0][nb][0];
#pragma unroll
                for (int mi = 0; mi < 4; ++mi)
#pragma unroll
                    for (int r = 0; r < 4; ++r) mx = fmaxf(mx, sacc[mi][nb][r]);
                mx = fmaxf(mx, __shfl_xor(mx, 16, 64));
                mx = fmaxf(mx, __shfl_xor(mx, 32, 64));
                float mnew  = fmaxf(mrow[nb], mx);
                float alpha = __builtin_amdgcn_exp2f(mrow[nb] - mnew);
                float ls = 0.f;
#pragma unroll
                for (int mi = 0; mi < 4; ++mi) {
                    short4v pk;
#pragma unroll
                    for (int r = 0; r < 4; ++r) {
                        float p = __builtin_amdgcn_exp2f(sacc[mi][nb][r] - mnew);
                        ls += p;
                        pk[r] = (short)f2bf(p);
                    }
                    *(short4v*)(PT + (wave * 32 + nb * 16 + l16) * 72 + mi * 16 + quad * 4) = pk;
                }
                ls += __shfl_xor(ls, 16, 64);
                ls += __shfl_xor(ls, 32, 64);
                lrow[nb] = lrow[nb] * alpha + ls;
                mrow[nb] = mnew;
#pragma unroll
                for (int mi3 = 0; mi3 < 4; ++mi3) Oacc[mi3][nb] *= alpha;
            }
            asm volatile("s_waitcnt lgkmcnt(0)" ::: "memory");

#pragma unroll
            for (int ks2 = 0; ks2 < 2; ++ks2) {
                short8 av[4], bp[2];
#pragma unroll
                for (int mi3 = 0; mi3 < 4; ++mi3)
                    av[mi3] = *(const short8*)(VT + (mi3 * 16 + l16) * 72 + ks2 * 32 + quad * 8);
#pragma unroll
                for (int nb = 0; nb < 2; ++nb)
                    bp[nb] = *(const short8*)(PT + (wave * 32 + nb * 16 + l16) * 72 + ks2 * 32 + quad * 8);
#pragma unroll
                for (int mi3 = 0; mi3 < 4; ++mi3)
#pragma unroll
                    for (int nb = 0; nb < 2; ++nb)
                        Oacc[mi3][nb] = __builtin_amdgcn_mfma_f32_16x16x32_bf16(
                            av[mi3], bp[nb], Oacc[mi3][nb], 0, 0, 0);
            }
        }

#pragma unroll
        for (int nb = 0; nb < 2; ++nb) {
            float inv = 1.0f / lrow[nb];
#pragma unroll
            for (int mi3 = 0; mi3 < 4; ++mi3) {
                short4v ov;
#pragma unroll
                for (int r = 0; r < 4; ++r)
                    ov[r] = (short)f2bf(Oacc[mi3][nb][r] * inv);
                *(short4v*)(PT + (wave * 32 + nb * 16 + l16) * 72 + mi3 * 16 + quad * 4) = ov;
            }
        }
        asm volatile("s_waitcnt lgkmcnt(0)" ::: "memory");
        {
            int ql = lane >> 1, dbase = (lane & 1) * 32;
            unsigned short* op = ctx + (tokbase + q0 + wave * 32 + ql) * Dd + h * HD + dbase;
            const unsigned short* lp = PT + (wave * 32 + ql) * 72 + dbase;
#pragma unroll
            for (int i = 0; i < 4; ++i)
                ((short8*)op)[i] = *(const short8*)(lp + i * 8);
        }
    }
}

// ---------------- launch ----------------
extern "C" void kernel_launch(void* const* d_in, const int* in_sizes, int n_in,
                              void* d_out, int out_size, void* d_ws, size_t ws_size,
                              hipStream_t stream)
{
    const float* x        = (const float*)d_in[0];
    const float* ln1_g    = (const float*)d_in[1];
    const float* ln1_b    = (const float*)d_in[2];
    const float* c_attn_w = (const float*)d_in[3];
    const float* c_attn_b = (const float*)d_in[4];
    const float* c_proj_w = (const float*)d_in[5];
    const float* c_proj_b = (const float*)d_in[6];
    const float* ln2_g    = (const float*)d_in[7];
    const float* ln2_b    = (const float*)d_in[8];
    const float* fc_w     = (const float*)d_in[9];
    const float* fc_b     = (const float*)d_in[10];
    const float* proj_w   = (const float*)d_in[11];
    const float* proj_b   = (const float*)d_in[12];
    float* out = (float*)d_out;

    char* p = (char*)d_ws;
    auto alloc = [&](size_t bytes) {
        void* r = (void*)p;
        p += (bytes + 255) & ~(size_t)255;
        return r;
    };
    unsigned short* WaP  = (unsigned short*)alloc((size_t)3072 * 1024 * 2);
    unsigned short* WpP  = (unsigned short*)alloc((size_t)1024 * 1024 * 2);
    unsigned short* WfP  = (unsigned short*)alloc((size_t)4096 * 1024 * 2);
    unsigned short* Wp2P = (unsigned short*)alloc((size_t)1024 * 4096 * 2);
    unsigned short* h1   = (unsigned short*)alloc((size_t)MTOK * 1024 * 2);
    unsigned short* qkv  = (unsigned short*)alloc((size_t)MTOK * 3072 * 2);
    unsigned short* ctx  = (unsigned short*)alloc((size_t)MTOK * 1024 * 2);
    float*          hmid = (float*)alloc((size_t)MTOK * 1024 * 4);
    unsigned short* h2   = (unsigned short*)alloc((size_t)MTOK * 1024 * 2);
    unsigned short* ff1  = (unsigned short*)alloc((size_t)MTOK * 4096 * 2);

    pack_w<<<(3072 / 16) * (1024 / 32) / 4, 256, 0, stream>>>(c_attn_w, WaP, 1024, 3072);
    pack_w<<<(1024 / 16) * (1024 / 32) / 4, 256, 0, stream>>>(c_proj_w, WpP, 1024, 1024);
    pack_w<<<(4096 / 16) * (1024 / 32) / 4, 256, 0, stream>>>(fc_w, WfP, 1024, 4096);
    pack_w<<<(1024 / 16) * (4096 / 32) / 4, 256, 0, stream>>>(proj_w, Wp2P, 4096, 1024);

    layernorm_bf16<<<MTOK, 256, 0, stream>>>(x, ln1_g, ln1_b, h1);
    // qkv: N=3072, BN=128 -> grid 32x24 = 768 blocks (3 exact CU rounds)
    gemm_v2<0, 4><<<dim3(32, 24), 512, 0, stream>>>(h1, WaP, c_attn_b, nullptr, qkv, MTOK, 3072, 1024);
    attn_mfma<<<Bb * Hh * 4, 256, 0, stream>>>(qkv, ctx);
    // proj: N=1024, BN=128 -> 32x8 = 256 blocks (1 round)
    gemm_v2<1, 4><<<dim3(32, 8), 512, 0, stream>>>(ctx, WpP, c_proj_b, x, hmid, MTOK, 1024, 1024);
    layernorm_bf16<<<MTOK, 256, 0, stream>>>(hmid, ln2_g, ln2_b, h2);
    // fc: N=4096, BN=256 -> 32x16 = 512 blocks (2 rounds)
    gemm_v2<2, 2><<<dim3(32, 16), 512, 0, stream>>>(h2, WfP, fc_b, nullptr, ff1, MTOK, 4096, 1024);
    // proj2: N=1024, K=4096, BN=128 -> 32x8 = 256 blocks (1 round)
    gemm_v2<1, 4><<<dim3(32, 8), 512, 0, stream>>>(ff1, Wp2P, proj_b, hmid, out, MTOK, 1024, 4096);
}

// Round 4
// 436.179 us; speedup vs baseline: 1.1733x; 1.1733x over previous
//
#include <hip/hip_runtime.h>
#include <cstdint>
#include <cmath>

// GPT-2 block: B=8, S=1024, D=1024, H=16, Hd=64.
// LN1 -> qkv GEMM -> MFMA flash attention -> proj GEMM(+res) -> LN2
//     -> fc GEMM(+fast GELU) -> proj2 GEMM(+res) -> out (fp32)
//
// gemm4b: BK=32, 4 rotating LDS buffers, counted-vmcnt pipeline.
//   Stage tile t+3 while reading tile t (buffer (t+3)&3 != t&3, (t+1)&3
//   -> WAR-safe by construction; round-3's 2-buffer depth-7 schedule raced).
//   Uniform L loads/tile -> one s_waitcnt vmcnt(2L) per tile BEFORE the
//   phase barrier (publishes staged data to all waves); never vmcnt(0).
//   A: chunk-XOR swizzle c^((row>>1)&3) applied on the global source
//      (gl2lds dest stays linear); reads use the same XOR -> 2-way max.
//   B: pre-packed fragment-major -> LDS copy is linear, reads lane-major.

#define Bb 8
#define Ss 1024
#define Dd 1024
#define Hh 16
#define HD 64
#define MTOK 8192  // B*S

typedef __attribute__((ext_vector_type(4))) float  floatx4;
typedef __attribute__((ext_vector_type(8))) short  short8;
typedef __attribute__((ext_vector_type(4))) short  short4v;

__device__ __forceinline__ float bf2f(unsigned short u) {
    return __uint_as_float(((unsigned int)u) << 16);
}
__device__ __forceinline__ unsigned short f2bf(float f) {
    unsigned int u = __float_as_uint(f);
    u += 0x7FFFu + ((u >> 16) & 1u);   // RNE
    return (unsigned short)(u >> 16);
}

__device__ __forceinline__ void gl2lds16(const void* g, void* l) {
    __builtin_amdgcn_global_load_lds(
        (__attribute__((address_space(1))) void*)(g),
        (__attribute__((address_space(3))) void*)(l),
        16, 0, 0);
}

template <int N> __device__ __forceinline__ void wait_vmcnt() {
    if constexpr (N == 6)       asm volatile("s_waitcnt vmcnt(6)"  ::: "memory");
    else if constexpr (N == 8)  asm volatile("s_waitcnt vmcnt(8)"  ::: "memory");
    else if constexpr (N == 12) asm volatile("s_waitcnt vmcnt(12)" ::: "memory");
    else                        asm volatile("s_waitcnt vmcnt(0)"  ::: "memory");
}

// ---------------- weight pack: fp32 [K][N] -> bf16 fragment-major ----------
// P[((nt*KC + kc)*64 + lane)*8 + j] = bf16(W[(kc*32 + (lane>>4)*8 + j)*N + nt*16 + (lane&15)])
__global__ __launch_bounds__(256) void pack_w(
    const float* __restrict__ W, unsigned short* __restrict__ P, int K, int N)
{
    const int KC = K >> 5;
    int tile = blockIdx.x * 4 + (threadIdx.x >> 6);
    int lane = threadIdx.x & 63;
    int nt = tile / KC, kc = tile - nt * KC;
    int l16 = lane & 15, quad = lane >> 4;
    const float* src = W + (size_t)(kc * 32 + quad * 8) * N + nt * 16 + l16;
    short8 o;
#pragma unroll
    for (int j = 0; j < 8; ++j) o[j] = (short)f2bf(src[(size_t)j * N]);
    *(short8*)(P + ((size_t)(nt * KC + kc) * 64 + lane) * 8) = o;
}

// ---------------- layernorm fp32 -> bf16 ----------------
__global__ __launch_bounds__(256) void layernorm_bf16(
    const float* __restrict__ X, const float* __restrict__ g,
    const float* __restrict__ b, unsigned short* __restrict__ Y)
{
    int row = blockIdx.x, t = threadIdx.x;
    const float4* xr = (const float4*)(X + (size_t)row * Dd);
    float4 v = xr[t];
    float s  = v.x + v.y + v.z + v.w;
    float s2 = v.x * v.x + v.y * v.y + v.z * v.z + v.w * v.w;
#pragma unroll
    for (int off = 32; off >= 1; off >>= 1) {
        s  += __shfl_down(s, off, 64);
        s2 += __shfl_down(s2, off, 64);
    }
    __shared__ float red[8];
    int wave = t >> 6, lane = t & 63;
    if (lane == 0) { red[wave] = s; red[4 + wave] = s2; }
    __syncthreads();
    float ts  = red[0] + red[1] + red[2] + red[3];
    float ts2 = red[4] + red[5] + red[6] + red[7];
    float mu  = ts * (1.0f / Dd);
    float var = ts2 * (1.0f / Dd) - mu * mu;
    float rstd = rsqrtf(var + 1e-5f);
    float4 gv = ((const float4*)g)[t];
    float4 bv = ((const float4*)b)[t];
    ushort4 o;
    o.x = f2bf((v.x - mu) * rstd * gv.x + bv.x);
    o.y = f2bf((v.y - mu) * rstd * gv.y + bv.y);
    o.z = f2bf((v.z - mu) * rstd * gv.z + bv.z);
    o.w = f2bf((v.w - mu) * rstd * gv.w + bv.w);
    ((ushort4*)(Y + (size_t)row * Dd))[t] = o;
}

// ---------------- gemm4b: 4-buffer BK=32 pipelined GEMM --------------------
// MODE 0: out bf16 = A@W + bias
// MODE 1: out fp32 = A@W + bias + res
// MODE 2: out bf16 = gelu_new(A@W + bias)
// BM in {256,128}; BN=256; 8 waves (2M x 4N).
template <int MODE, int BM>
__global__ __launch_bounds__(512, 1) void gemm4b(
    const unsigned short* __restrict__ A,   // [M][K] bf16 row-major
    const unsigned short* __restrict__ BP,  // packed weight frags
    const float* __restrict__ bias,
    const float* __restrict__ res,
    void* __restrict__ out,
    int M, int N, int K)
{
    constexpr int MI  = BM / 32;        // m-frags per wave (8 / 4)
    constexpr int NPH = MI / 4;         // phases per K-tile (2 / 1)
    constexpr int LA  = BM / 128;       // A loads/thread/tile (2 / 1)
    constexpr int ASZ = BM * 32;        // shorts per A buffer
    constexpr int WVC = 2 * (LA + 2);   // steady-state vmcnt (8 / 6)
    __shared__ short LD[4 * ASZ + 4 * 8192];  // 128 KB / 96 KB

    const int tid  = threadIdx.x;
    const int wave = tid >> 6, lane = tid & 63;
    const int quad = lane >> 4, l16 = lane & 15;
    const int wrow = wave >> 2, wcol = wave & 3;
    const size_t rowA0 = (size_t)blockIdx.x * BM;
    const int NT = K >> 5;              // 32-deep K-tiles (= pack KC)
    const int ntbase = blockIdx.y * 16;

    // A staging sources (linear LDS dest; XOR swizzle on global side):
    // idx = tid + r*512 -> row rr = idx>>2 (0..BM-1), chunk slot cc = idx&3;
    // slot cc holds source chunk cc ^ ((rr>>1)&3).
    const unsigned short* aSrc[LA];
#pragma unroll
    for (int r = 0; r < LA; ++r) {
        int idx = tid + r * 512;
        int rr = idx >> 2, cc = idx & 3;
        aSrc[r] = A + (rowA0 + rr) * (size_t)K + ((cc ^ ((rr >> 1) & 3)) * 8);
    }
    // B staging sources: idx -> local nt = idx>>6, frag element (idx&63)*8.
    const unsigned short* bSrc[2];
#pragma unroll
    for (int r = 0; r < 2; ++r) {
        int idx = tid + r * 512;
        bSrc[r] = BP + (size_t)(ntbase + (idx >> 6)) * NT * 512 + (idx & 63) * 8;
    }

    floatx4 acc[MI][4] = {};

    // prologue: stage tiles 0..2 (buffers 0..2), wait for tile 0 only.
#pragma unroll
    for (int g = 0; g < 3; ++g) {
#pragma unroll
        for (int r = 0; r < LA; ++r)
            gl2lds16(aSrc[r] + g * 32, LD + g * ASZ + (tid + r * 512) * 8);
#pragma unroll
        for (int r = 0; r < 2; ++r)
            gl2lds16(bSrc[r] + (size_t)g * 512,
                     LD + 4 * ASZ + g * 8192 + (tid + r * 512) * 8);
    }
    wait_vmcnt<WVC>();
    __builtin_amdgcn_s_barrier();

    const int aswz = (l16 >> 1) & 3;
    for (int t = 0; t < NT; ++t) {
        const int buf  = t & 3;
        const int ts   = (t + 3 < NT) ? t + 3 : NT - 1;  // tail: same bytes
        const int sbuf = ts & 3;
        const short* Ab = LD + buf * ASZ;
        const short* Bt = LD + 4 * ASZ + buf * 8192;
        short8 bfr[4];
#pragma unroll
        for (int n = 0; n < 4; ++n)
            bfr[n] = *(const short8*)(Bt + ((wcol * 4 + n) * 64 + lane) * 8);
#pragma unroll
        for (int mq = 0; mq < NPH; ++mq) {
            short8 af[4];
#pragma unroll
            for (int i = 0; i < 4; ++i) {
                const int R = wrow * (MI * 16) + mq * 64 + i * 16 + l16;
                af[i] = *(const short8*)(Ab + R * 32 + ((quad ^ aswz) * 8));
            }
            if (NPH == 1 || mq == 0) {      // stage A(t+3)
#pragma unroll
                for (int r = 0; r < LA; ++r)
                    gl2lds16(aSrc[r] + (size_t)ts * 32,
                             LD + sbuf * ASZ + (tid + r * 512) * 8);
            }
            if (NPH == 1 || mq == 1) {      // stage B(t+3), counted wait
#pragma unroll
                for (int r = 0; r < 2; ++r)
                    gl2lds16(bSrc[r] + (size_t)ts * 512,
                             LD + 4 * ASZ + sbuf * 8192 + (tid + r * 512) * 8);
                wait_vmcnt<WVC>();          // tile t+1 landed; t+2,t+3 in flight
            }
            __builtin_amdgcn_s_setprio(1);
#pragma unroll
            for (int i = 0; i < 4; ++i)
#pragma unroll
                for (int n = 0; n < 4; ++n)
                    acc[mq * 4 + i][n] = __builtin_amdgcn_mfma_f32_16x16x32_bf16(
                        af[i], bfr[n], acc[mq * 4 + i][n], 0, 0, 0);
            __builtin_amdgcn_s_setprio(0);
            asm volatile("s_barrier" ::: "memory");
        }
    }

    // epilogue
    const size_t colB = (size_t)blockIdx.y * 256 + wcol * 64;
#pragma unroll
    for (int mi = 0; mi < MI; ++mi) {
#pragma unroll
        for (int ni = 0; ni < 4; ++ni) {
            size_t row = rowA0 + wrow * (MI * 16) + mi * 16 + quad * 4;
            size_t col = colB + ni * 16 + l16;
            float bc = bias[col];
#pragma unroll
            for (int r = 0; r < 4; ++r) {
                float v = acc[mi][ni][r] + bc;
                if (MODE == 0) {
                    ((unsigned short*)out)[(row + r) * N + col] = f2bf(v);
                } else if (MODE == 1) {
                    ((float*)out)[(row + r) * N + col] = v + res[(row + r) * N + col];
                } else {
                    float u = 0.7978845608028654f * (v + 0.044715f * v * v * v);
                    float e = __builtin_amdgcn_exp2f(-2.8853900817779268f * u);
                    float gl = v * __builtin_amdgcn_rcpf(1.0f + e);
                    ((unsigned short*)out)[(row + r) * N + col] = f2bf(gl);
                }
            }
        }
    }
}

// ---------------- MFMA flash attention (causal) ----------------
__global__ __launch_bounds__(256, 2) void attn_mfma(
    const unsigned short* __restrict__ qkv,  // [B*S][3072] bf16 q|k|v
    unsigned short* __restrict__ ctx)        // [B*S][1024] bf16
{
    __shared__ unsigned short Ks[64 * 72];
    __shared__ unsigned short VT[64 * 72];
    __shared__ unsigned short PT[128 * 72];

    const int tid  = threadIdx.x;
    const int wave = tid >> 6, lane = tid & 63;
    const int quad = lane >> 4, l16 = lane & 15;
    const int blk = blockIdx.x;
    const int c4 = blk & 3, h = (blk >> 2) & 15, b = blk >> 6;
    const size_t tokbase = (size_t)b * Ss;

    const int skey = tid & 63;
    const int sseg = tid >> 6;

    for (int ci = 0; ci < 2; ++ci) {
        const int chunk = ci ? (7 - c4) : c4;
        const int q0 = chunk * 128;

        short8 qf[2][2];
#pragma unroll
        for (int nb = 0; nb < 2; ++nb)
#pragma unroll
            for (int ks = 0; ks < 2; ++ks) {
                const short8* qp = (const short8*)(qkv
                    + (tokbase + q0 + wave * 32 + nb * 16 + l16) * 3072
                    + h * HD + ks * 32 + quad * 8);
                short8 v = *qp, o;
#pragma unroll
                for (int j = 0; j < 8; ++j)
                    o[j] = (short)f2bf(bf2f((unsigned short)v[j]) * 0.18033688011112042f);
                qf[nb][ks] = o;
            }

        floatx4 Oacc[4][2] = {};
        float mrow[2] = {-3.0e38f, -3.0e38f};
        float lrow[2] = {0.f, 0.f};

        const int nkt = 2 * (chunk + 1);
        for (int kt = 0; kt < nkt; ++kt) {
            __syncthreads();
            {
                const short8* kp = (const short8*)(qkv
                    + (tokbase + kt * 64 + skey) * 3072 + Dd + h * HD + sseg * 16);
                short8 k0 = kp[0], k1 = kp[1];
                *(short8*)(Ks + skey * 72 + sseg * 16)     = k0;
                *(short8*)(Ks + skey * 72 + sseg * 16 + 8) = k1;
                const short8* vp = (const short8*)(qkv
                    + (tokbase + kt * 64 + skey) * 3072 + 2 * Dd + h * HD + sseg * 16);
                short8 v0 = vp[0], v1 = vp[1];
#pragma unroll
                for (int j = 0; j < 8; ++j) {
                    VT[(sseg * 16 + j) * 72 + skey]     = (unsigned short)v0[j];
                    VT[(sseg * 16 + 8 + j) * 72 + skey] = (unsigned short)v1[j];
                }
            }
            __syncthreads();

            floatx4 sacc[4][2] = {};
#pragma unroll
            for (int ks = 0; ks < 2; ++ks) {
                short8 af[4];
#pragma unroll
                for (int mi = 0; mi < 4; ++mi)
                    af[mi] = *(const short8*)(Ks + (mi * 16 + l16) * 72 + ks * 32 + quad * 8);
#pragma unroll
                for (int mi = 0; mi < 4; ++mi)
#pragma unroll
                    for (int nb = 0; nb < 2; ++nb)
                        sacc[mi][nb] = __builtin_amdgcn_mfma_f32_16x16x32_bf16(
                            af[mi], qf[nb][ks], sacc[mi][nb], 0, 0, 0);
            }

            if (kt >= 2 * chunk) {
                const int dk = (kt - 2 * chunk) * 64;
#pragma unroll
                for (int nb = 0; nb < 2; ++nb) {
                    int qrow = wave * 32 + nb * 16 + l16;
#pragma unroll
                    for (int mi = 0; mi < 4; ++mi)
#pragma unroll
                        for (int r = 0; r < 4; ++r)
                            if (dk + mi * 16 + quad * 4 + r > qrow)
                                sacc[mi][nb][r] = -3.0e38f;
                }
            }

#pragma unroll
            for (int nb = 0; nb < 2; ++nb) {
                float mx = sacc[0][nb][0];
#pragma unroll
                for (int mi = 0; mi < 4; ++mi)
#pragma unroll
                    for (int r = 0; r < 4; ++r) mx = fmaxf(mx, sacc[mi][nb][r]);
                mx = fmaxf(mx, __shfl_xor(mx, 16, 64));
                mx = fmaxf(mx, __shfl_xor(mx, 32, 64));
                float mnew  = fmaxf(mrow[nb], mx);
                float alpha = __builtin_amdgcn_exp2f(mrow[nb] - mnew);
                float ls = 0.f;
#pragma unroll
                for (int mi = 0; mi < 4; ++mi) {
                    short4v pk;
#pragma unroll
                    for (int r = 0; r < 4; ++r) {
                        float p = __builtin_amdgcn_exp2f(sacc[mi][nb][r] - mnew);
                        ls += p;
                        pk[r] = (short)f2bf(p);
                    }
                    *(short4v*)(PT + (wave * 32 + nb * 16 + l16) * 72 + mi * 16 + quad * 4) = pk;
                }
                ls += __shfl_xor(ls, 16, 64);
                ls += __shfl_xor(ls, 32, 64);
                lrow[nb] = lrow[nb] * alpha + ls;
                mrow[nb] = mnew;
#pragma unroll
                for (int mi3 = 0; mi3 < 4; ++mi3) Oacc[mi3][nb] *= alpha;
            }
            asm volatile("s_waitcnt lgkmcnt(0)" ::: "memory");

#pragma unroll
            for (int ks2 = 0; ks2 < 2; ++ks2) {
                short8 av[4], bp[2];
#pragma unroll
                for (int mi3 = 0; mi3 < 4; ++mi3)
                    av[mi3] = *(const short8*)(VT + (mi3 * 16 + l16) * 72 + ks2 * 32 + quad * 8);
#pragma unroll
                for (int nb = 0; nb < 2; ++nb)
                    bp[nb] = *(const short8*)(PT + (wave * 32 + nb * 16 + l16) * 72 + ks2 * 32 + quad * 8);
#pragma unroll
                for (int mi3 = 0; mi3 < 4; ++mi3)
#pragma unroll
                    for (int nb = 0; nb < 2; ++nb)
                        Oacc[mi3][nb] = __builtin_amdgcn_mfma_f32_16x16x32_bf16(
                            av[mi3], bp[nb], Oacc[mi3][nb], 0, 0, 0);
            }
        }

#pragma unroll
        for (int nb = 0; nb < 2; ++nb) {
            float inv = 1.0f / lrow[nb];
#pragma unroll
            for (int mi3 = 0; mi3 < 4; ++mi3) {
                short4v ov;
#pragma unroll
                for (int r = 0; r < 4; ++r)
                    ov[r] = (short)f2bf(Oacc[mi3][nb][r] * inv);
                *(short4v*)(PT + (wave * 32 + nb * 16 + l16) * 72 + mi3 * 16 + quad * 4) = ov;
            }
        }
        asm volatile("s_waitcnt lgkmcnt(0)" ::: "memory");
        {
            int ql = lane >> 1, dbase = (lane & 1) * 32;
            unsigned short* op = ctx + (tokbase + q0 + wave * 32 + ql) * Dd + h * HD + dbase;
            const unsigned short* lp = PT + (wave * 32 + ql) * 72 + dbase;
#pragma unroll
            for (int i = 0; i < 4; ++i)
                ((short8*)op)[i] = *(const short8*)(lp + i * 8);
        }
    }
}

// ---------------- launch ----------------
extern "C" void kernel_launch(void* const* d_in, const int* in_sizes, int n_in,
                              void* d_out, int out_size, void* d_ws, size_t ws_size,
                              hipStream_t stream)
{
    const float* x        = (const float*)d_in[0];
    const float* ln1_g    = (const float*)d_in[1];
    const float* ln1_b    = (const float*)d_in[2];
    const float* c_attn_w = (const float*)d_in[3];
    const float* c_attn_b = (const float*)d_in[4];
    const float* c_proj_w = (const float*)d_in[5];
    const float* c_proj_b = (const float*)d_in[6];
    const float* ln2_g    = (const float*)d_in[7];
    const float* ln2_b    = (const float*)d_in[8];
    const float* fc_w     = (const float*)d_in[9];
    const float* fc_b     = (const float*)d_in[10];
    const float* proj_w   = (const float*)d_in[11];
    const float* proj_b   = (const float*)d_in[12];
    float* out = (float*)d_out;

    char* p = (char*)d_ws;
    auto alloc = [&](size_t bytes) {
        void* r = (void*)p;
        p += (bytes + 255) & ~(size_t)255;
        return r;
    };
    unsigned short* WaP  = (unsigned short*)alloc((size_t)3072 * 1024 * 2);
    unsigned short* WpP  = (unsigned short*)alloc((size_t)1024 * 1024 * 2);
    unsigned short* WfP  = (unsigned short*)alloc((size_t)4096 * 1024 * 2);
    unsigned short* Wp2P = (unsigned short*)alloc((size_t)1024 * 4096 * 2);
    unsigned short* h1   = (unsigned short*)alloc((size_t)MTOK * 1024 * 2);
    unsigned short* qkv  = (unsigned short*)alloc((size_t)MTOK * 3072 * 2);
    unsigned short* ctx  = (unsigned short*)alloc((size_t)MTOK * 1024 * 2);
    float*          hmid = (float*)alloc((size_t)MTOK * 1024 * 4);
    unsigned short* h2   = (unsigned short*)alloc((size_t)MTOK * 1024 * 2);
    unsigned short* ff1  = (unsigned short*)alloc((size_t)MTOK * 4096 * 2);

    pack_w<<<(3072 / 16) * (1024 / 32) / 4, 256, 0, stream>>>(c_attn_w, WaP, 1024, 3072);
    pack_w<<<(1024 / 16) * (1024 / 32) / 4, 256, 0, stream>>>(c_proj_w, WpP, 1024, 1024);
    pack_w<<<(4096 / 16) * (1024 / 32) / 4, 256, 0, stream>>>(fc_w, WfP, 1024, 4096);
    pack_w<<<(1024 / 16) * (4096 / 32) / 4, 256, 0, stream>>>(proj_w, Wp2P, 4096, 1024);

    layernorm_bf16<<<MTOK, 256, 0, stream>>>(x, ln1_g, ln1_b, h1);
    // qkv: BM=128, grid 64x12 = 768 blocks (3 exact CU rounds)
    gemm4b<0, 128><<<dim3(64, 12), 512, 0, stream>>>(h1, WaP, c_attn_b, nullptr, qkv, MTOK, 3072, 1024);
    attn_mfma<<<Bb * Hh * 4, 256, 0, stream>>>(qkv, ctx);
    // proj: BM=128, grid 64x4 = 256 blocks (1 round)
    gemm4b<1, 128><<<dim3(64, 4), 512, 0, stream>>>(ctx, WpP, c_proj_b, x, hmid, MTOK, 1024, 1024);
    layernorm_bf16<<<MTOK, 256, 0, stream>>>(hmid, ln2_g, ln2_b, h2);
    // fc: BM=256, grid 32x16 = 512 blocks (2 rounds)
    gemm4b<2, 256><<<dim3(32, 16), 512, 0, stream>>>(h2, WfP, fc_b, nullptr, ff1, MTOK, 4096, 1024);
    // proj2: BM=128, K=4096, grid 64x4 = 256 blocks (1 round)
    gemm4b<1, 128><<<dim3(64, 4), 512, 0, stream>>>(ff1, Wp2P, proj_b, hmid, out, MTOK, 1024, 4096);
}